// Round 5
// baseline (269.986 us; speedup 1.0000x reference)
//
#include <hip/hip_runtime.h>
#include <hip/hip_bf16.h>
#include <cstdint>

// Problem constants
#define NTOK 8192
#define DIN  1024
#define DOUT 1024
#define NEXP 8

typedef __attribute__((ext_vector_type(8)))  __bf16 bf16x8;
typedef __attribute__((ext_vector_type(4)))  float  f32x4;

__device__ __forceinline__ unsigned short f2bf(float f) {
    unsigned int u = __builtin_bit_cast(unsigned int, f);
    u += 0x7FFFu + ((u >> 16) & 1u);   // round-to-nearest-even
    return (unsigned short)(u >> 16);
}

__device__ __forceinline__ void cp16(const void* gsrc, void* ldst) {
    __builtin_amdgcn_global_load_lds(
        (const __attribute__((address_space(1))) void*)gsrc,
        (__attribute__((address_space(3))) void*)ldst,
        16, 0, 0);
}

#define BAR() asm volatile("s_barrier" ::: "memory")

// ---------------------------------------------------------------------------
// Prep kernel (unchanged):
//   blocks [0, 2048):     We [e][k][o] fp32 -> WebT [e][o][k] bf16
//   blocks [2048, 2304):  gate softmax(x@Wg+bg) + x -> bf16
// ---------------------------------------------------------------------------
__global__ __launch_bounds__(256) void prep_kernel(
    const float* __restrict__ x, const float* __restrict__ We,
    const float* __restrict__ Wg, const float* __restrict__ bg,
    unsigned short* __restrict__ xb, unsigned short* __restrict__ wt,
    float* __restrict__ g)
{
    __shared__ float smem[12416];

    int t = threadIdx.x;

    if (blockIdx.x < 2048) {
        unsigned short* tile = (unsigned short*)smem;   // [64][72]
        int b = blockIdx.x;
        int e  = b >> 8;
        int kt = (b >> 4) & 15;
        int ot = b & 15;

        const float* src = We + ((size_t)e << 20) + (size_t)(kt * 64) * DOUT + ot * 64;
        unsigned short* dst = wt + ((size_t)e << 20) + (size_t)(ot * 64) * DIN + kt * 64;

        int kl = t >> 2;
        int og = (t & 3) * 16;
#pragma unroll
        for (int c = 0; c < 4; ++c) {
            int o = og + c * 4;
            float4 v = *(const float4*)&src[(size_t)kl * DOUT + o];
            ushort4 u;
            u.x = f2bf(v.x); u.y = f2bf(v.y); u.z = f2bf(v.z); u.w = f2bf(v.w);
            *(ushort4*)&tile[kl * 72 + o] = u;
        }
        __syncthreads();
        int ol = t >> 2;
        int kg = (t & 3) * 16;
        unsigned short tmp[16];
#pragma unroll
        for (int i = 0; i < 16; ++i) tmp[i] = tile[(kg + i) * 72 + ol];
        *(uint4*)&dst[(size_t)ol * DIN + kg]     = *(uint4*)&tmp[0];
        *(uint4*)&dst[(size_t)ol * DIN + kg + 8] = *(uint4*)&tmp[8];
    } else {
        float* WgL = smem;          // [8][1024] transposed Wg
        float* xL  = smem + 8192;   // [32][132] x chunk
        int n0 = (blockIdx.x - 2048) * 32;

#pragma unroll
        for (int q = 0; q < 8; ++q) {
            int fidx = q * 256 + t;
            int k  = fidx >> 1;
            int eh = (fidx & 1) * 4;
            float4 v = *(const float4*)&Wg[(size_t)k * 8 + eh];
            WgL[(eh + 0) * 1024 + k] = v.x;
            WgL[(eh + 1) * 1024 + k] = v.y;
            WgL[(eh + 2) * 1024 + k] = v.z;
            WgL[(eh + 3) * 1024 + k] = v.w;
        }

        int tt = t & 31;
        int e  = t >> 5;
        float acc = 0.f;

        for (int c = 0; c < 8; ++c) {
            int kb = c * 128;
#pragma unroll
            for (int q = 0; q < 4; ++q) {
                int fidx = q * 256 + t;
                int row = fidx >> 5;
                int kk  = (fidx & 31) * 4;
                float4 v = *(const float4*)&x[(size_t)(n0 + row) * DIN + kb + kk];
                ushort4 u;
                u.x = f2bf(v.x); u.y = f2bf(v.y); u.z = f2bf(v.z); u.w = f2bf(v.w);
                *(ushort4*)&xb[(size_t)(n0 + row) * DIN + kb + kk] = u;
                *(float4*)&xL[row * 132 + kk] = v;
            }
            __syncthreads();
#pragma unroll
            for (int kk = 0; kk < 128; kk += 4) {
                float4 xv = *(const float4*)&xL[tt * 132 + kk];
                float4 wv = *(const float4*)&WgL[e * 1024 + kb + kk];
                acc += xv.x * wv.x + xv.y * wv.y + xv.z * wv.z + xv.w * wv.w;
            }
            __syncthreads();
        }

        float* lg = xL;
        lg[tt * 8 + e] = acc + bg[e];
        __syncthreads();
        if (t < 32) {
            float l[8];
#pragma unroll
            for (int i = 0; i < 8; ++i) l[i] = lg[t * 8 + i];
            float m = l[0];
#pragma unroll
            for (int i = 1; i < 8; ++i) m = fmaxf(m, l[i]);
            float s = 0.f;
#pragma unroll
            for (int i = 0; i < 8; ++i) { l[i] = __expf(l[i] - m); s += l[i]; }
            float inv = 1.0f / s;
            float4 p0 = make_float4(l[0]*inv, l[1]*inv, l[2]*inv, l[3]*inv);
            float4 p1 = make_float4(l[4]*inv, l[5]*inv, l[6]*inv, l[7]*inv);
            *(float4*)&g[(size_t)(n0 + tt) * 8]     = p0;
            *(float4*)&g[(size_t)(n0 + tt) * 8 + 4] = p1;
        }
    }
}

// ---------------------------------------------------------------------------
// Main MoE GEMM — R3's read-ratio geometry at R0's occupancy:
//  - BM=128 x BN=32 x 8 experts, BK=32, 256 thr (4 waves = 2M x 2N)
//  - LDS dbuf = 2 x (A 8KB + B 16KB) = 48 KB -> TWO blocks/CU (the R0
//    regime): sibling block's waves absorb barrier/latency stalls (m114),
//    which R1-R4's 1-block/CU schedules all exposed (flat 147-156 us)
//  - per wave per tile: 12 ds_read_b128 per 32 MFMA (0.375, A-frags reused
//    across all 8 experts); acc[8][4] = 128 VGPR, merge once in epilogue
//  - ONE barrier + one vmcnt(0) per K-tile; the drain covers cp16s issued
//    a full tile earlier (~400 cyc) -> no stall in steady state
//  - 64B-row swizzle: phys_chunk = chunk ^ ((row>>1)&3). Bank-quad math
//    gives the verified-free fingerprint: 8 distinct quads per 8 lanes,
//    2-way per 16 lanes (free). Staging dest linear (elem = tid*8).
//  - XCD swizzle: bn XCD-local (B slab 2 MB, L2-resident per XCD)
// ---------------------------------------------------------------------------
__global__ __launch_bounds__(256, 2) void moe_gemm_kernel(
    const unsigned short* __restrict__ xb,   // [NTOK][DIN] bf16
    const unsigned short* __restrict__ wt,   // [E][DOUT][DIN] bf16
    const float* __restrict__ g,             // [NTOK][E]
    const float* __restrict__ be,             // [E][DOUT]
    float* __restrict__ out)                 // [NTOK][DOUT]
{
    __shared__ unsigned short lA[2][128 * 32];   // 2 x 8 KB
    __shared__ unsigned short lB[2][256 * 32];   // 2 x 16 KB (8e x 32col)

    int bid = blockIdx.x;                 // 0..2047
    int xcd = bid & 7;
    int idx = bid >> 3;                   // 0..255
    int bn  = xcd * 4 + (idx & 3);        // 0..31, XCD-local B panels
    int bm  = idx >> 2;                   // 0..63

    int tid  = threadIdx.x;               // 0..255
    int lane = tid & 63;
    int wave = tid >> 6;                  // 0..3
    int wm   = wave >> 1;                 // 0..1 (64-row slab of 128)
    int wn   = wave & 1;                  // 0..1 (16-col slab of 32)

    int rA   = lane & 15;
    int quad = lane >> 4;                 // 0..3 (k-chunk of 32)
    int kp   = ((quad ^ ((rA >> 1) & 3)) << 3);   // phys chunk elem offset

    int aRow[4], bRow[8];
#pragma unroll
    for (int i = 0; i < 4; ++i) aRow[i] = (wm * 64 + i * 16 + rA) * 32;
#pragma unroll
    for (int e = 0; e < 8; ++e) bRow[e] = (e * 32 + wn * 16 + rA) * 32;

    // staging geometry: thread covers (row = r*64 + tid>>2, phys chunk tid&3);
    // phys chunk holds logical chunk (tid&3) ^ ((row>>1)&3); dest linear tid*8
    int srow   = tid >> 2;                            // 0..63
    int soff   = ((tid & 3) ^ ((srow >> 1) & 3)) << 3;   // src k-elem offset
    int sdst   = tid * 8;                             // LDS dest elems

    const unsigned short* aS0 = xb + (size_t)(bm * 128 +  0 + srow) * DIN + soff;
    const unsigned short* aS1 = xb + (size_t)(bm * 128 + 64 + srow) * DIN + soff;
    int eh   = srow >> 5;                 // 0..1
    int colS = srow & 31;
    const unsigned short* bS0 = wt + ((size_t)(0 + eh) << 20) + (size_t)(bn * 32 + colS) * DIN + soff;
    const unsigned short* bS1 = wt + ((size_t)(2 + eh) << 20) + (size_t)(bn * 32 + colS) * DIN + soff;
    const unsigned short* bS2 = wt + ((size_t)(4 + eh) << 20) + (size_t)(bn * 32 + colS) * DIN + soff;
    const unsigned short* bS3 = wt + ((size_t)(6 + eh) << 20) + (size_t)(bn * 32 + colS) * DIN + soff;

#define STAGE(b, tt)                                                           \
    {   size_t ko = (size_t)(tt) * 32;                                         \
        cp16(aS0 + ko, &lA[b][0 * 2048 + sdst]);                               \
        cp16(aS1 + ko, &lA[b][1 * 2048 + sdst]);                               \
        cp16(bS0 + ko, &lB[b][0 * 2048 + sdst]);                               \
        cp16(bS1 + ko, &lB[b][1 * 2048 + sdst]);                               \
        cp16(bS2 + ko, &lB[b][2 * 2048 + sdst]);                               \
        cp16(bS3 + ko, &lB[b][3 * 2048 + sdst]); }

    // ---- prologue: stage K-tile 0 into buf0 ----
    STAGE(0, 0);

    f32x4 acc[8][4] = {};   // [expert][i-block]

    asm volatile("s_waitcnt vmcnt(0)" ::: "memory");
    BAR();

#pragma unroll 1
    for (int t = 0; t < 32; ++t) {
        int c = t & 1, n = c ^ 1;
        if (t < 31) STAGE(n, t + 1);

        const unsigned short* A = lA[c];
        const unsigned short* B = lB[c];
        bf16x8 af[4], bf[8];
#pragma unroll
        for (int i = 0; i < 4; ++i) af[i] = *(const bf16x8*)&A[aRow[i] + kp];
#pragma unroll
        for (int e = 0; e < 8; ++e) bf[e] = *(const bf16x8*)&B[bRow[e] + kp];

        __builtin_amdgcn_s_setprio(1);
#pragma unroll
        for (int e = 0; e < 8; ++e)
#pragma unroll
            for (int i = 0; i < 4; ++i)
                acc[e][i] = __builtin_amdgcn_mfma_f32_16x16x32_bf16(
                    af[i], bf[e], acc[e][i], 0, 0, 0);
        __builtin_amdgcn_s_setprio(0);

        if (t < 31) {
            asm volatile("s_waitcnt vmcnt(0)" ::: "memory");
            BAR();   // publishes tile t+1; fences buf c for restage at t+1
        }
    }

    // ---- epilogue: out[n,col] = sum_e g[n,e] * (acc_e + be[e,col]) ----
    int colg = bn * 32 + wn * 16 + rA;
    float bcol[8];
#pragma unroll
    for (int e = 0; e < 8; ++e) bcol[e] = be[(size_t)e * DOUT + colg];
#pragma unroll
    for (int i = 0; i < 4; ++i) {
        int rbase = bm * 128 + wm * 64 + i * 16 + quad * 4;
#pragma unroll
        for (int rr = 0; rr < 4; ++rr) {
            const float* gp = &g[(size_t)(rbase + rr) * 8];
            float4 g0 = *(const float4*)gp;
            float4 g1 = *(const float4*)(gp + 4);
            float s = g0.x * (acc[0][i][rr] + bcol[0])
                    + g0.y * (acc[1][i][rr] + bcol[1])
                    + g0.z * (acc[2][i][rr] + bcol[2])
                    + g0.w * (acc[3][i][rr] + bcol[3])
                    + g1.x * (acc[4][i][rr] + bcol[4])
                    + g1.y * (acc[5][i][rr] + bcol[5])
                    + g1.z * (acc[6][i][rr] + bcol[6])
                    + g1.w * (acc[7][i][rr] + bcol[7]);
            out[(size_t)(rbase + rr) * DOUT + colg] = s;
        }
    }
}

// ---------------------------------------------------------------------------
extern "C" void kernel_launch(void* const* d_in, const int* in_sizes, int n_in,
                              void* d_out, int out_size, void* d_ws, size_t ws_size,
                              hipStream_t stream)
{
    const float* x  = (const float*)d_in[0];   // [8192,1024]
    const float* We = (const float*)d_in[1];   // [8,1024,1024]
    const float* be = (const float*)d_in[2];   // [8,1024]
    const float* Wg = (const float*)d_in[3];   // [1024,8]
    const float* bg = (const float*)d_in[4];   // [8]
    float* out = (float*)d_out;                // [8192,1024]

    // workspace: xb (16.78MB bf16) | WebT (16.78MB bf16) | g (256KB f32)
    unsigned short* xb = (unsigned short*)d_ws;
    unsigned short* wt = xb + (size_t)NTOK * DIN;
    float* g = (float*)(wt + (size_t)NEXP * DOUT * DIN);

    prep_kernel<<<2048 + 256, 256, 0, stream>>>(x, We, Wg, bg, xb, wt, g);
    moe_gemm_kernel<<<(NTOK / 128) * (DOUT / 32), 256, 0, stream>>>(xb, wt, g, be, out);
}

// Round 6
// 268.206 us; speedup vs baseline: 1.0066x; 1.0066x over previous
//
#include <hip/hip_runtime.h>
#include <hip/hip_bf16.h>
#include <cstdint>

// Problem constants
#define NTOK 8192
#define DIN  1024
#define DOUT 1024
#define NEXP 8

typedef __attribute__((ext_vector_type(8)))  __bf16 bf16x8;
typedef __attribute__((ext_vector_type(4)))  float  f32x4;

__device__ __forceinline__ unsigned short f2bf(float f) {
    unsigned int u = __builtin_bit_cast(unsigned int, f);
    u += 0x7FFFu + ((u >> 16) & 1u);   // round-to-nearest-even
    return (unsigned short)(u >> 16);
}

__device__ __forceinline__ void cp16(const void* gsrc, void* ldst) {
    __builtin_amdgcn_global_load_lds(
        (const __attribute__((address_space(1))) void*)gsrc,
        (__attribute__((address_space(3))) void*)ldst,
        16, 0, 0);
}

#define BAR() asm volatile("s_barrier" ::: "memory")

// ---------------------------------------------------------------------------
// Prep kernel (unchanged):
//   blocks [0, 2048):     We [e][k][o] fp32 -> WebT [e][o][k] bf16
//   blocks [2048, 2304):  gate softmax(x@Wg+bg) + x -> bf16
// ---------------------------------------------------------------------------
__global__ __launch_bounds__(256) void prep_kernel(
    const float* __restrict__ x, const float* __restrict__ We,
    const float* __restrict__ Wg, const float* __restrict__ bg,
    unsigned short* __restrict__ xb, unsigned short* __restrict__ wt,
    float* __restrict__ g)
{
    __shared__ float smem[12416];

    int t = threadIdx.x;

    if (blockIdx.x < 2048) {
        unsigned short* tile = (unsigned short*)smem;   // [64][72]
        int b = blockIdx.x;
        int e  = b >> 8;
        int kt = (b >> 4) & 15;
        int ot = b & 15;

        const float* src = We + ((size_t)e << 20) + (size_t)(kt * 64) * DOUT + ot * 64;
        unsigned short* dst = wt + ((size_t)e << 20) + (size_t)(ot * 64) * DIN + kt * 64;

        int kl = t >> 2;
        int og = (t & 3) * 16;
#pragma unroll
        for (int c = 0; c < 4; ++c) {
            int o = og + c * 4;
            float4 v = *(const float4*)&src[(size_t)kl * DOUT + o];
            ushort4 u;
            u.x = f2bf(v.x); u.y = f2bf(v.y); u.z = f2bf(v.z); u.w = f2bf(v.w);
            *(ushort4*)&tile[kl * 72 + o] = u;
        }
        __syncthreads();
        int ol = t >> 2;
        int kg = (t & 3) * 16;
        unsigned short tmp[16];
#pragma unroll
        for (int i = 0; i < 16; ++i) tmp[i] = tile[(kg + i) * 72 + ol];
        *(uint4*)&dst[(size_t)ol * DIN + kg]     = *(uint4*)&tmp[0];
        *(uint4*)&dst[(size_t)ol * DIN + kg + 8] = *(uint4*)&tmp[8];
    } else {
        float* WgL = smem;          // [8][1024] transposed Wg
        float* xL  = smem + 8192;   // [32][132] x chunk
        int n0 = (blockIdx.x - 2048) * 32;

#pragma unroll
        for (int q = 0; q < 8; ++q) {
            int fidx = q * 256 + t;
            int k  = fidx >> 1;
            int eh = (fidx & 1) * 4;
            float4 v = *(const float4*)&Wg[(size_t)k * 8 + eh];
            WgL[(eh + 0) * 1024 + k] = v.x;
            WgL[(eh + 1) * 1024 + k] = v.y;
            WgL[(eh + 2) * 1024 + k] = v.z;
            WgL[(eh + 3) * 1024 + k] = v.w;
        }

        int tt = t & 31;
        int e  = t >> 5;
        float acc = 0.f;

        for (int c = 0; c < 8; ++c) {
            int kb = c * 128;
#pragma unroll
            for (int q = 0; q < 4; ++q) {
                int fidx = q * 256 + t;
                int row = fidx >> 5;
                int kk  = (fidx & 31) * 4;
                float4 v = *(const float4*)&x[(size_t)(n0 + row) * DIN + kb + kk];
                ushort4 u;
                u.x = f2bf(v.x); u.y = f2bf(v.y); u.z = f2bf(v.z); u.w = f2bf(v.w);
                *(ushort4*)&xb[(size_t)(n0 + row) * DIN + kb + kk] = u;
                *(float4*)&xL[row * 132 + kk] = v;
            }
            __syncthreads();
#pragma unroll
            for (int kk = 0; kk < 128; kk += 4) {
                float4 xv = *(const float4*)&xL[tt * 132 + kk];
                float4 wv = *(const float4*)&WgL[e * 1024 + kb + kk];
                acc += xv.x * wv.x + xv.y * wv.y + xv.z * wv.z + xv.w * wv.w;
            }
            __syncthreads();
        }

        float* lg = xL;
        lg[tt * 8 + e] = acc + bg[e];
        __syncthreads();
        if (t < 32) {
            float l[8];
#pragma unroll
            for (int i = 0; i < 8; ++i) l[i] = lg[t * 8 + i];
            float m = l[0];
#pragma unroll
            for (int i = 1; i < 8; ++i) m = fmaxf(m, l[i]);
            float s = 0.f;
#pragma unroll
            for (int i = 0; i < 8; ++i) { l[i] = __expf(l[i] - m); s += l[i]; }
            float inv = 1.0f / s;
            float4 p0 = make_float4(l[0]*inv, l[1]*inv, l[2]*inv, l[3]*inv);
            float4 p1 = make_float4(l[4]*inv, l[5]*inv, l[6]*inv, l[7]*inv);
            *(float4*)&g[(size_t)(n0 + tt) * 8]     = p0;
            *(float4*)&g[(size_t)(n0 + tt) * 8 + 4] = p1;
        }
    }
}

// ---------------------------------------------------------------------------
// Main MoE GEMM — R5 geometry + software-pipelined (cross-phase) frag reads:
//  - BM=128 x BN=32 x 8 experts, BK=32, 256 thr (4 waves = 2M x 2N),
//    LDS dbuf 48 KB -> 2+ blocks/CU; layout/staging/swizzle byte-identical
//    to R5 (measured: SQ_LDS_BANK_CONFLICT = 0)
//  - m201/m196 lever: every phase's ds_reads feed the NEXT phase's MFMA.
//      P0: stage(t+1); read bf[4..7](t);  MFMA e0-3 (frags from prev P1)
//      P1: vmcnt(0)+BAR (t+1 published; loads issued a phase earlier);
//          MFMA e4-7 (bfB from P0) interleaved with 8 ds_reads of tile
//          t+1's af/bfA (i-outer MFMA order frees af[i] early for WAR refill)
//    -> no MFMA cluster ever waits on its own phase's lgkmcnt chain
//  - 1 barrier + 1 vmcnt per tile (same counts as R5 — delta is read placement)
//  - buffer hazard: stage(t+1)->buf n vs last reads of buf n (t-1's P0) are
//    separated by t-1.P1's vmcnt+barrier (m201's verified discipline)
//  - regs ~200 (acc 128 + 3 frag sets 48 + addr) -> 2 waves/SIMD holds
// ---------------------------------------------------------------------------
__global__ __launch_bounds__(256, 2) void moe_gemm_kernel(
    const unsigned short* __restrict__ xb,   // [NTOK][DIN] bf16
    const unsigned short* __restrict__ wt,   // [E][DOUT][DIN] bf16
    const float* __restrict__ g,             // [NTOK][E]
    const float* __restrict__ be,            // [E][DOUT]
    float* __restrict__ out)                 // [NTOK][DOUT]
{
    __shared__ unsigned short lA[2][128 * 32];   // 2 x 8 KB
    __shared__ unsigned short lB[2][256 * 32];   // 2 x 16 KB (8e x 32col)

    int bid = blockIdx.x;                 // 0..2047
    int xcd = bid & 7;
    int idx = bid >> 3;                   // 0..255
    int bn  = xcd * 4 + (idx & 3);        // 0..31, XCD-local B panels
    int bm  = idx >> 2;                   // 0..63

    int tid  = threadIdx.x;               // 0..255
    int lane = tid & 63;
    int wave = tid >> 6;                  // 0..3
    int wm   = wave >> 1;                 // 0..1 (64-row slab of 128)
    int wn   = wave & 1;                  // 0..1 (16-col slab of 32)

    int rA   = lane & 15;
    int quad = lane >> 4;                 // 0..3 (k-chunk of 32)
    int kp   = ((quad ^ ((rA >> 1) & 3)) << 3);   // phys chunk elem offset

    int aRow[4], bRow[8];
#pragma unroll
    for (int i = 0; i < 4; ++i) aRow[i] = (wm * 64 + i * 16 + rA) * 32;
#pragma unroll
    for (int e = 0; e < 8; ++e) bRow[e] = (e * 32 + wn * 16 + rA) * 32;

    // staging geometry: thread covers (row = r*64 + tid>>2, phys chunk tid&3);
    // phys chunk holds logical chunk (tid&3) ^ ((row>>1)&3); dest linear tid*8
    int srow   = tid >> 2;                            // 0..63
    int soff   = ((tid & 3) ^ ((srow >> 1) & 3)) << 3;   // src k-elem offset
    int sdst   = tid * 8;                             // LDS dest elems

    const unsigned short* aS0 = xb + (size_t)(bm * 128 +  0 + srow) * DIN + soff;
    const unsigned short* aS1 = xb + (size_t)(bm * 128 + 64 + srow) * DIN + soff;
    int eh   = srow >> 5;                 // 0..1
    int colS = srow & 31;
    const unsigned short* bS0 = wt + ((size_t)(0 + eh) << 20) + (size_t)(bn * 32 + colS) * DIN + soff;
    const unsigned short* bS1 = wt + ((size_t)(2 + eh) << 20) + (size_t)(bn * 32 + colS) * DIN + soff;
    const unsigned short* bS2 = wt + ((size_t)(4 + eh) << 20) + (size_t)(bn * 32 + colS) * DIN + soff;
    const unsigned short* bS3 = wt + ((size_t)(6 + eh) << 20) + (size_t)(bn * 32 + colS) * DIN + soff;

#define STAGE(b, tt)                                                           \
    {   size_t ko = (size_t)(tt) * 32;                                         \
        cp16(aS0 + ko, &lA[b][0 * 2048 + sdst]);                               \
        cp16(aS1 + ko, &lA[b][1 * 2048 + sdst]);                               \
        cp16(bS0 + ko, &lB[b][0 * 2048 + sdst]);                               \
        cp16(bS1 + ko, &lB[b][1 * 2048 + sdst]);                               \
        cp16(bS2 + ko, &lB[b][2 * 2048 + sdst]);                               \
        cp16(bS3 + ko, &lB[b][3 * 2048 + sdst]); }

    // ---- prologue: stage K-tile 0 into buf0, preload its P0 fragments ----
    STAGE(0, 0);

    f32x4 acc[8][4] = {};   // [expert][i-block]
    bf16x8 af[4], bfA[4], bfB[4];

    asm volatile("s_waitcnt vmcnt(0)" ::: "memory");
    BAR();

#pragma unroll
    for (int i = 0; i < 4; ++i) af[i]  = *(const bf16x8*)&lA[0][aRow[i] + kp];
#pragma unroll
    for (int e = 0; e < 4; ++e) bfA[e] = *(const bf16x8*)&lB[0][bRow[e] + kp];

#pragma unroll 1
    for (int t = 0; t < 32; ++t) {
        int c = t & 1, n = c ^ 1;

        // ---- P0: stage t+1; read bf[4..7](t); MFMA e0-3 (preloaded frags) ----
        if (t < 31) STAGE(n, t + 1);
#pragma unroll
        for (int e = 0; e < 4; ++e)
            bfB[e] = *(const bf16x8*)&lB[c][bRow[e + 4] + kp];

        __builtin_amdgcn_s_setprio(1);
#pragma unroll
        for (int e = 0; e < 4; ++e)
#pragma unroll
            for (int i = 0; i < 4; ++i)
                acc[e][i] = __builtin_amdgcn_mfma_f32_16x16x32_bf16(
                    af[i], bfA[e], acc[e][i], 0, 0, 0);
        __builtin_amdgcn_s_setprio(0);

        // ---- P1: publish t+1; MFMA e4-7 interleaved with t+1 frag reads ----
        if (t < 31) {
            asm volatile("s_waitcnt vmcnt(0)" ::: "memory");
            BAR();
        }
        __builtin_amdgcn_s_setprio(1);
#pragma unroll
        for (int i = 0; i < 4; ++i) {
#pragma unroll
            for (int e = 0; e < 4; ++e)
                acc[4 + e][i] = __builtin_amdgcn_mfma_f32_16x16x32_bf16(
                    af[i], bfB[e], acc[4 + e][i], 0, 0, 0);
            // af[i] dead after its 4 MFMAs above -> WAR refill can interleave
            af[i] = *(const bf16x8*)&lA[n][aRow[i] + kp];
        }
        __builtin_amdgcn_s_setprio(0);
#pragma unroll
        for (int e = 0; e < 4; ++e)
            bfA[e] = *(const bf16x8*)&lB[n][bRow[e] + kp];
        // (t=31: refills read stale buf harmlessly; results unused)
    }

    // ---- epilogue: out[n,col] = sum_e g[n,e] * (acc_e + be[e,col]) ----
    int colg = bn * 32 + wn * 16 + rA;
    float bcol[8];
#pragma unroll
    for (int e = 0; e < 8; ++e) bcol[e] = be[(size_t)e * DOUT + colg];
#pragma unroll
    for (int i = 0; i < 4; ++i) {
        int rbase = bm * 128 + wm * 64 + i * 16 + quad * 4;
#pragma unroll
        for (int rr = 0; rr < 4; ++rr) {
            const float* gp = &g[(size_t)(rbase + rr) * 8];
            float4 g0 = *(const float4*)gp;
            float4 g1 = *(const float4*)(gp + 4);
            float s = g0.x * (acc[0][i][rr] + bcol[0])
                    + g0.y * (acc[1][i][rr] + bcol[1])
                    + g0.z * (acc[2][i][rr] + bcol[2])
                    + g0.w * (acc[3][i][rr] + bcol[3])
                    + g1.x * (acc[4][i][rr] + bcol[4])
                    + g1.y * (acc[5][i][rr] + bcol[5])
                    + g1.z * (acc[6][i][rr] + bcol[6])
                    + g1.w * (acc[7][i][rr] + bcol[7]);
            out[(size_t)(rbase + rr) * DOUT + colg] = s;
        }
    }
}

// ---------------------------------------------------------------------------
extern "C" void kernel_launch(void* const* d_in, const int* in_sizes, int n_in,
                              void* d_out, int out_size, void* d_ws, size_t ws_size,
                              hipStream_t stream)
{
    const float* x  = (const float*)d_in[0];   // [8192,1024]
    const float* We = (const float*)d_in[1];   // [8,1024,1024]
    const float* be = (const float*)d_in[2];   // [8,1024]
    const float* Wg = (const float*)d_in[3];   // [1024,8]
    const float* bg = (const float*)d_in[4];   // [8]
    float* out = (float*)d_out;                // [8192,1024]

    // workspace: xb (16.78MB bf16) | WebT (16.78MB bf16) | g (256KB f32)
    unsigned short* xb = (unsigned short*)d_ws;
    unsigned short* wt = xb + (size_t)NTOK * DIN;
    float* g = (float*)(wt + (size_t)NEXP * DOUT * DIN);

    prep_kernel<<<2048 + 256, 256, 0, stream>>>(x, We, Wg, bg, xb, wt, g);
    moe_gemm_kernel<<<(NTOK / 128) * (DOUT / 32), 256, 0, stream>>>(xb, wt, g, be, out);
}

// Round 7
// 261.629 us; speedup vs baseline: 1.0319x; 1.0251x over previous
//
#include <hip/hip_runtime.h>
#include <hip/hip_bf16.h>
#include <cstdint>

// Problem constants
#define NTOK 8192
#define DIN  1024
#define DOUT 1024
#define NEXP 8

typedef __attribute__((ext_vector_type(8)))  __bf16 bf16x8;
typedef __attribute__((ext_vector_type(4)))  float  f32x4;

__device__ __forceinline__ unsigned short f2bf(float f) {
    unsigned int u = __builtin_bit_cast(unsigned int, f);
    u += 0x7FFFu + ((u >> 16) & 1u);   // round-to-nearest-even
    return (unsigned short)(u >> 16);
}

__device__ __forceinline__ void cp16(const void* gsrc, void* ldst) {
    __builtin_amdgcn_global_load_lds(
        (const __attribute__((address_space(1))) void*)gsrc,
        (__attribute__((address_space(3))) void*)ldst,
        16, 0, 0);
}

// ---------------------------------------------------------------------------
// Prep kernel (unchanged; non-GEMM time ~112us is harness-fixed — invariant
// across R1..R7's very different prep structures):
//   blocks [0, 2048):     We [e][k][o] fp32 -> WebT [e][o][k] bf16
//   blocks [2048, 2304):  gate softmax(x@Wg+bg) + x -> bf16
// ---------------------------------------------------------------------------
__global__ __launch_bounds__(256) void prep_kernel(
    const float* __restrict__ x, const float* __restrict__ We,
    const float* __restrict__ Wg, const float* __restrict__ bg,
    unsigned short* __restrict__ xb, unsigned short* __restrict__ wt,
    float* __restrict__ g)
{
    __shared__ float smem[12416];

    int t = threadIdx.x;

    if (blockIdx.x < 2048) {
        unsigned short* tile = (unsigned short*)smem;   // [64][72]
        int b = blockIdx.x;
        int e  = b >> 8;
        int kt = (b >> 4) & 15;
        int ot = b & 15;

        const float* src = We + ((size_t)e << 20) + (size_t)(kt * 64) * DOUT + ot * 64;
        unsigned short* dst = wt + ((size_t)e << 20) + (size_t)(ot * 64) * DIN + kt * 64;

        int kl = t >> 2;
        int og = (t & 3) * 16;
#pragma unroll
        for (int c = 0; c < 4; ++c) {
            int o = og + c * 4;
            float4 v = *(const float4*)&src[(size_t)kl * DOUT + o];
            ushort4 u;
            u.x = f2bf(v.x); u.y = f2bf(v.y); u.z = f2bf(v.z); u.w = f2bf(v.w);
            *(ushort4*)&tile[kl * 72 + o] = u;
        }
        __syncthreads();
        int ol = t >> 2;
        int kg = (t & 3) * 16;
        unsigned short tmp[16];
#pragma unroll
        for (int i = 0; i < 16; ++i) tmp[i] = tile[(kg + i) * 72 + ol];
        *(uint4*)&dst[(size_t)ol * DIN + kg]     = *(uint4*)&tmp[0];
        *(uint4*)&dst[(size_t)ol * DIN + kg + 8] = *(uint4*)&tmp[8];
    } else {
        float* WgL = smem;          // [8][1024] transposed Wg
        float* xL  = smem + 8192;   // [32][132] x chunk
        int n0 = (blockIdx.x - 2048) * 32;

#pragma unroll
        for (int q = 0; q < 8; ++q) {
            int fidx = q * 256 + t;
            int k  = fidx >> 1;
            int eh = (fidx & 1) * 4;
            float4 v = *(const float4*)&Wg[(size_t)k * 8 + eh];
            WgL[(eh + 0) * 1024 + k] = v.x;
            WgL[(eh + 1) * 1024 + k] = v.y;
            WgL[(eh + 2) * 1024 + k] = v.z;
            WgL[(eh + 3) * 1024 + k] = v.w;
        }

        int tt = t & 31;
        int e  = t >> 5;
        float acc = 0.f;

        for (int c = 0; c < 8; ++c) {
            int kb = c * 128;
#pragma unroll
            for (int q = 0; q < 4; ++q) {
                int fidx = q * 256 + t;
                int row = fidx >> 5;
                int kk  = (fidx & 31) * 4;
                float4 v = *(const float4*)&x[(size_t)(n0 + row) * DIN + kb + kk];
                ushort4 u;
                u.x = f2bf(v.x); u.y = f2bf(v.y); u.z = f2bf(v.z); u.w = f2bf(v.w);
                *(ushort4*)&xb[(size_t)(n0 + row) * DIN + kb + kk] = u;
                *(float4*)&xL[row * 132 + kk] = v;
            }
            __syncthreads();
#pragma unroll
            for (int kk = 0; kk < 128; kk += 4) {
                float4 xv = *(const float4*)&xL[tt * 132 + kk];
                float4 wv = *(const float4*)&WgL[e * 1024 + kb + kk];
                acc += xv.x * wv.x + xv.y * wv.y + xv.z * wv.z + xv.w * wv.w;
            }
            __syncthreads();
        }

        float* lg = xL;
        lg[tt * 8 + e] = acc + bg[e];
        __syncthreads();
        if (t < 32) {
            float l[8];
#pragma unroll
            for (int i = 0; i < 8; ++i) l[i] = lg[t * 8 + i];
            float m = l[0];
#pragma unroll
            for (int i = 1; i < 8; ++i) m = fmaxf(m, l[i]);
            float s = 0.f;
#pragma unroll
            for (int i = 0; i < 8; ++i) { l[i] = __expf(l[i] - m); s += l[i]; }
            float inv = 1.0f / s;
            float4 p0 = make_float4(l[0]*inv, l[1]*inv, l[2]*inv, l[3]*inv);
            float4 p1 = make_float4(l[4]*inv, l[5]*inv, l[6]*inv, l[7]*inv);
            *(float4*)&g[(size_t)(n0 + tt) * 8]     = p0;
            *(float4*)&g[(size_t)(n0 + tt) * 8 + 4] = p1;
        }
    }
}

// ---------------------------------------------------------------------------
// Main MoE GEMM — BK=128 windows (64 barrier-pairs, R7's amortization) built
// from TWO 128B-stride BK=64 sub-buffers each for A and B (R2's verified
// conflict-free read pattern). Measured rule (R2/R3/R7): b128 fragment reads
// from 256B-strided LDS rows cost exactly 4 conflict-cyc/read regardless of
// swizzle (R3=R7=2^24 exactly); 128B stride + XOR swizzle is free (R2=2^19).
// This session's R1-R6 falsified every alternative: counted-vmcnt schedules,
// 4-phase split, 32x32 MFMA, expert-innermost, 3-blocks/CU, cross-phase
// pipelined reads — all land 147-156us vs this kernel's 137.5us. The fused
// MoE register wall (acc 128 + outAcc 128 regs) caps occupancy at 2 waves/
// SIMD, where every 2-phase-class schedule measures 38-44% MfmaUtil; this
// config is the measured optimum of that class.
//  - lA0+lA1+lB0+lB1 = 64 KB -> 2 blocks/CU
//  - staging: 16 cp16/thread/window; dest wave-uniform base + lane*16
//  - fragment reads byte-identical to R2's measured-free pattern
//  - merge reads g/be from global (L1-hot; FETCH stayed 86 MB in R7)
//  - regs ~128 VGPR + 128 acc < 256/wave unified cap (R4 spill lesson)
// ---------------------------------------------------------------------------
__global__ __launch_bounds__(256, 2) void moe_gemm_kernel(
    const unsigned short* __restrict__ xb,   // [NTOK][DIN] bf16
    const unsigned short* __restrict__ wt,   // [E][DOUT][DIN] bf16
    const float* __restrict__ g,             // [NTOK][E]
    const float* __restrict__ be,            // [E][DOUT]
    float* __restrict__ out)                 // [NTOK][DOUT]
{
    __shared__ unsigned short lA0[128 * 64];   // 16 KB, k in [0,64)
    __shared__ unsigned short lA1[128 * 64];   // 16 KB, k in [64,128)
    __shared__ unsigned short lB0[128 * 64];
    __shared__ unsigned short lB1[128 * 64];

    int bid = blockIdx.x;
    int bm = (bid & 7) * 8 + ((bid >> 3) & 7);   // 0..63, XCD-local A slab
    int bn = bid >> 6;                            // 0..7
    int tid = threadIdx.x;
    int lane = tid & 63;
    int wave = tid >> 6;
    int wm = wave >> 1;        // 0..1
    int wn = wave & 1;         // 0..1

    const unsigned short* aBase = xb + (size_t)(bm * 128) * DIN;
    const unsigned short* bBase0 = wt + (size_t)(bn * 128) * DIN;

    // R2 staging geometry per sub-buffer: lane covers (row rowS+32j, physical
    // chunk lane&7); physical chunk holds logical chunk (lane&7)^(row&7).
    int rowS = wave * 8 + (lane >> 3);                    // row in 32-row group
    int k8   = (((lane & 7) ^ (lane >> 3)) * 8);          // swizzled source k
    int rA   = lane & 15;                                 // fragment row/col
    int quad = lane >> 4;                                 // 0..3
    int swz  = rA & 7;

    f32x4 outAcc[4][4] = {};

#pragma unroll 1
    for (int e = 0; e < NEXP; ++e) {
        f32x4 acc[4][4] = {};
        const unsigned short* bBase = bBase0 + ((size_t)e << 20);

#pragma unroll 1
        for (int kt = 0; kt < 8; ++kt) {
            int kb = kt * 128;
            __syncthreads();
#pragma unroll
            for (int j = 0; j < 4; ++j) {
                int row = j * 32 + rowS;
                size_t so0 = (size_t)row * DIN + kb + k8;
                size_t so1 = so0 + 64;
                int dst = j * 2048 + wave * 512;
                cp16(aBase + so0, &lA0[dst]);
                cp16(aBase + so1, &lA1[dst]);
                cp16(bBase + so0, &lB0[dst]);
                cp16(bBase + so1, &lB1[dst]);
            }
            __syncthreads();
#pragma unroll
            for (int ks = 0; ks < 2; ++ks) {
                int kc = ks * 4 + quad;               // logical chunk 0..7
                int kp = (kc ^ swz) * 8;              // swizzled offset
                bf16x8 af[4], bfr[4];
                // ---- half 0: k in [0,64) ----
#pragma unroll
                for (int i = 0; i < 4; ++i)
                    af[i] = *(const bf16x8*)&lA0[(wm * 64 + i * 16 + rA) * 64 + kp];
#pragma unroll
                for (int j = 0; j < 4; ++j)
                    bfr[j] = *(const bf16x8*)&lB0[(wn * 64 + j * 16 + rA) * 64 + kp];
#pragma unroll
                for (int i = 0; i < 4; ++i)
#pragma unroll
                    for (int j = 0; j < 4; ++j)
                        acc[i][j] = __builtin_amdgcn_mfma_f32_16x16x32_bf16(
                            af[i], bfr[j], acc[i][j], 0, 0, 0);
                // ---- half 1: k in [64,128) ----
#pragma unroll
                for (int i = 0; i < 4; ++i)
                    af[i] = *(const bf16x8*)&lA1[(wm * 64 + i * 16 + rA) * 64 + kp];
#pragma unroll
                for (int j = 0; j < 4; ++j)
                    bfr[j] = *(const bf16x8*)&lB1[(wn * 64 + j * 16 + rA) * 64 + kp];
#pragma unroll
                for (int i = 0; i < 4; ++i)
#pragma unroll
                    for (int j = 0; j < 4; ++j)
                        acc[i][j] = __builtin_amdgcn_mfma_f32_16x16x32_bf16(
                            af[i], bfr[j], acc[i][j], 0, 0, 0);
            }
        }

        // merge: outAcc += g[row,e] * (acc + be[e,col]); g/be L1-hot global
        float bv[4];
#pragma unroll
        for (int j = 0; j < 4; ++j)
            bv[j] = be[(size_t)e * DOUT + bn * 128 + wn * 64 + j * 16 + rA];
#pragma unroll
        for (int i = 0; i < 4; ++i) {
            int rbase = bm * 128 + wm * 64 + i * 16 + quad * 4;
            float g0 = g[(size_t)(rbase + 0) * 8 + e];
            float g1 = g[(size_t)(rbase + 1) * 8 + e];
            float g2 = g[(size_t)(rbase + 2) * 8 + e];
            float g3 = g[(size_t)(rbase + 3) * 8 + e];
#pragma unroll
            for (int j = 0; j < 4; ++j) {
                outAcc[i][j].x += g0 * (acc[i][j].x + bv[j]);
                outAcc[i][j].y += g1 * (acc[i][j].y + bv[j]);
                outAcc[i][j].z += g2 * (acc[i][j].z + bv[j]);
                outAcc[i][j].w += g3 * (acc[i][j].w + bv[j]);
            }
        }
    }

    // epilogue: C layout col = lane&15, row = quad*4 + reg
#pragma unroll
    for (int i = 0; i < 4; ++i) {
        int rowb = bm * 128 + wm * 64 + i * 16 + quad * 4;
#pragma unroll
        for (int j = 0; j < 4; ++j) {
            int col = bn * 128 + wn * 64 + j * 16 + rA;
            out[(size_t)(rowb + 0) * DOUT + col] = outAcc[i][j].x;
            out[(size_t)(rowb + 1) * DOUT + col] = outAcc[i][j].y;
            out[(size_t)(rowb + 2) * DOUT + col] = outAcc[i][j].z;
            out[(size_t)(rowb + 3) * DOUT + col] = outAcc[i][j].w;
        }
    }
}

// ---------------------------------------------------------------------------
extern "C" void kernel_launch(void* const* d_in, const int* in_sizes, int n_in,
                              void* d_out, int out_size, void* d_ws, size_t ws_size,
                              hipStream_t stream)
{
    const float* x  = (const float*)d_in[0];   // [8192,1024]
    const float* We = (const float*)d_in[1];   // [8,1024,1024]
    const float* be = (const float*)d_in[2];   // [8,1024]
    const float* Wg = (const float*)d_in[3];   // [1024,8]
    const float* bg = (const float*)d_in[4];   // [8]
    float* out = (float*)d_out;                // [8192,1024]

    // workspace: xb (16.78MB bf16) | WebT (16.78MB bf16) | g (256KB f32)
    unsigned short* xb = (unsigned short*)d_ws;
    unsigned short* wt = xb + (size_t)NTOK * DIN;
    float* g = (float*)(wt + (size_t)NEXP * DOUT * DIN);

    prep_kernel<<<2048 + 256, 256, 0, stream>>>(x, We, Wg, bg, xb, wt, g);
    moe_gemm_kernel<<<(NTOK / 128) * (DOUT / 128), 256, 0, stream>>>(xb, wt, g, be, out);
}